// Round 5
// baseline (40.984 us; speedup 1.0000x reference)
//
#include <hip/hip_runtime.h>
#include <hip/hip_bf16.h>

typedef __attribute__((ext_vector_type(8))) short short8;
typedef __attribute__((ext_vector_type(16))) float f32x16;
typedef __attribute__((ext_vector_type(4))) float fx4;
typedef __attribute__((ext_vector_type(4))) unsigned uint4v;

#define LOG2E_F 1.4426950408889634f

// ws layout:
//   ushort kb   [8000][8]  bf16                        @ elem 0
//   ushort cq   [8000][8]  bf16 (pre-scaled by log2e)  @ elem 65536
//   ushort vfrag key-permuted B-frag-ready tiles       @ elem 131072
//   f32    pls  [128 qt][16 kp][2 qgrp][2 g][32 qi]    @ f32  elem 524288  (byte 2 MiB)
//   u32    pacc [128 qt][16 kp][64 q][32 col]          @ u32  elem 1048576 (byte 4 MiB)
//          pacc word = pk2(ctx[q][col], ctx[q][col+32])
#define KB_OFF   0u
#define CQ_OFF   65536u
#define VF_OFF   131072u
#define PLS_F    524288u
#define PACC_U   1048576u

__device__ __forceinline__ float fast_exp2(float v) {
#if __has_builtin(__builtin_amdgcn_exp2f)
    return __builtin_amdgcn_exp2f(v);
#else
    return exp2f(v);
#endif
}

__device__ __forceinline__ unsigned short f2bfu(float f) {
    unsigned short u;
    __hip_bfloat16 h = __float2bfloat16(f);
    __builtin_memcpy(&u, &h, 2);
    return u;
}

// two f32 -> one u32 of 2 bf16 (compiler fuses into v_cvt_pk_bf16_f32)
__device__ __forceinline__ unsigned pk2(float lo, float hi) {
    return (unsigned)f2bfu(lo) | ((unsigned)f2bfu(hi) << 16);
}

__device__ __forceinline__ short8 cvt8(fx4 a, fx4 b) {
    uint4v u;
    u[0] = pk2(a[0], a[1]);
    u[1] = pk2(a[2], a[3]);
    u[2] = pk2(b[0], b[1]);
    u[3] = pk2(b[2], b[3]);
    return __builtin_bit_cast(short8, u);
}

// ---------------- Phase A: MFMA projections ----------------
// C[8000x96] = X[8000x64] @ Wcomb[64x96]; cols 0-7 kb, 8-15 cq(*log2e),
// 16-79 vfrag (key-permuted), 80-95 zero. 125 blocks x 2 waves x 32 rows.
__global__ __launch_bounds__(128, 1) void pam_proj(
    const float* __restrict__ x,
    const float* __restrict__ Wb,
    const float* __restrict__ Wc,
    const float* __restrict__ Wd,
    unsigned short* __restrict__ ws)
{
    __shared__ alignas(16) unsigned short Wt[96][72];   // [col][k]

    const int tid = threadIdx.x;
    // Wd: 4096 elems, col fast -> coalesced global reads
#pragma unroll
    for (int i = 0; i < 32; ++i) {
        int e = i * 128 + tid;
        int col = e & 63, k = e >> 6;
        Wt[16 + col][k] = f2bfu(Wd[k * 64 + col]);
    }
    // Wb/Wc: 1024 elems (tiny)
#pragma unroll
    for (int i = 0; i < 8; ++i) {
        int e = i * 128 + tid;
        int c = e & 15, k = e >> 4;
        float w = (c < 8) ? Wb[k * 8 + c] : Wc[k * 8 + (c - 8)] * LOG2E_F;
        Wt[c][k] = f2bfu(w);
    }
    // zero cols 80-95 (pad): 16*72 = 1152 elems
#pragma unroll
    for (int i = 0; i < 9; ++i) {
        int e = i * 128 + tid;
        if (e < 1152) Wt[80 + e / 72][e - (e / 72) * 72] = 0;
    }
    __syncthreads();

    const int wave = tid >> 6, lane = tid & 63;
    const int l31 = lane & 31, g = lane >> 5;
    const int rowbase = blockIdx.x * 64 + wave * 32;    // 125*64 = 8000 exact

    // B frags: col = ct*32 + l31, k = kk*16 + g*8 + e
    short8 bfrag[3][4];
#pragma unroll
    for (int ct = 0; ct < 3; ++ct)
#pragma unroll
        for (int kk = 0; kk < 4; ++kk)
            bfrag[ct][kk] = *reinterpret_cast<const short8*>(&Wt[ct * 32 + l31][kk * 16 + g * 8]);

    // A frags: row = rowbase + l31, k = kk*16 + g*8 + e
    const float* xr = x + (size_t)(rowbase + l31) * 64 + g * 8;
    short8 afrag[4];
#pragma unroll
    for (int kk = 0; kk < 4; ++kk) {
        fx4 a = *reinterpret_cast<const fx4*>(xr + kk * 16);
        fx4 b = *reinterpret_cast<const fx4*>(xr + kk * 16 + 4);
        afrag[kk] = cvt8(a, b);
    }

    f32x16 acc[3] = {};
#pragma unroll
    for (int kk = 0; kk < 4; ++kk)
#pragma unroll
        for (int ct = 0; ct < 3; ++ct)
            acc[ct] = __builtin_amdgcn_mfma_f32_32x32x16_bf16(afrag[kk], bfrag[ct][kk], acc[ct], 0, 0, 0);

#pragma unroll
    for (int ct = 0; ct < 3; ++ct) {
        const int col = ct * 32 + l31;
#pragma unroll
        for (int r = 0; r < 16; ++r) {
            const int row = rowbase + (r & 3) + 8 * (r >> 2) + 4 * g;
            const unsigned short hv = f2bfu(acc[ct][r]);
            if (col < 8) {
                ws[KB_OFF + row * 8u + col] = hv;
            } else if (col < 16) {
                ws[CQ_OFF + row * 8u + (col - 8)] = hv;
            } else if (col < 80) {
                const unsigned j  = col - 16;
                const unsigned t5 = row & 31u;
                const unsigned ks = t5 >> 4;
                const unsigned rr = t5 & 15u;
                const unsigned gg = (rr >> 2) & 1u;
                const unsigned ee = (rr & 3u) + ((rr >> 3) << 2);
                ws[VF_OFF + (row >> 5) * 2048u + ks * 1024u + gg * 512u + j * 8u + ee] = hv;
            }
        }
    }
}

// ---------------- Phase B: flash attention, QW=64/wave, no LDS ----------------
// 512 blocks x 4 waves. kp = bid&15 (key part, shared by block's waves -> L1
// V reuse), qt = (bid>>4)*4 + wave in [0,128), active if qt<125.
// Per step (32 keys): S^T = mfma(kb,cq0/1); e = exp2; pack; 8 PV mfma.
__global__ __launch_bounds__(256, 2) void pam_attn(
    const unsigned short* __restrict__ ws,
    float* __restrict__ wsf,
    unsigned* __restrict__ wsu)
{
    const int tid  = threadIdx.x;
    const int wave = tid >> 6;
    const int lane = tid & 63;
    const int l31  = lane & 31;
    const int g    = lane >> 5;
    const int kp   = blockIdx.x & 15;
    const int qt   = (blockIdx.x >> 4) * 4 + wave;
    if (qt >= 125) return;                 // no barriers below
    const int qbase = qt * 64;

    const short8* kbp = reinterpret_cast<const short8*>(ws + KB_OFF);
    const short8* cqp = reinterpret_cast<const short8*>(ws + CQ_OFF);
    const short8* vp  = reinterpret_cast<const short8*>(ws + VF_OFF);

    short8 cf0 = {}, cf1 = {};
    if (lane < 32) {
        cf0 = cqp[qbase + l31];
        cf1 = cqp[qbase + 32 + l31];
    }

    f32x16 acc00 = {}, acc01 = {}, acc10 = {}, acc11 = {};
    float ls0 = 0.f, ls1 = 0.f;

    const int s0 = (250 * kp) >> 4;
    const int s1 = (250 * (kp + 1)) >> 4;

    short8 kf = {};
    if (lane < 32) kf = kbp[s0 * 32 + l31];
    const int vb = s0 * 256 + g * 64 + l31;
    short8 v00 = vp[vb];
    short8 v01 = vp[vb + 32];
    short8 v10 = vp[vb + 128];
    short8 v11 = vp[vb + 160];

    for (int s = s0; s < s1; ++s) {
        const int sn = s + 1;
        short8 kfn = {};
        short8 n00 = {}, n01 = {}, n10 = {}, n11 = {};
        if (sn < s1) {
            if (lane < 32) kfn = kbp[sn * 32 + l31];
            const int nb = sn * 256 + g * 64 + l31;
            n00 = vp[nb];
            n01 = vp[nb + 32];
            n10 = vp[nb + 128];
            n11 = vp[nb + 160];
        }

        f32x16 z = {};
        const f32x16 st0 = __builtin_amdgcn_mfma_f32_32x32x16_bf16(kf, cf0, z, 0, 0, 0);
        const f32x16 st1 = __builtin_amdgcn_mfma_f32_32x32x16_bf16(kf, cf1, z, 0, 0, 0);

        // ---- q-group 0 ----
        {
            float e[16];
#pragma unroll
            for (int r = 0; r < 16; ++r) e[r] = fast_exp2(st0[r]);
            ls0 += ((e[0] + e[1]) + (e[2] + e[3])) + ((e[4] + e[5]) + (e[6] + e[7]))
                 + ((e[8] + e[9]) + (e[10] + e[11])) + ((e[12] + e[13]) + (e[14] + e[15]));
            uint4v u0, u1;
#pragma unroll
            for (int p = 0; p < 4; ++p) u0[p] = pk2(e[2 * p], e[2 * p + 1]);
#pragma unroll
            for (int p = 0; p < 4; ++p) u1[p] = pk2(e[8 + 2 * p], e[9 + 2 * p]);
            const short8 af0 = __builtin_bit_cast(short8, u0);
            const short8 af1 = __builtin_bit_cast(short8, u1);
            acc00 = __builtin_amdgcn_mfma_f32_32x32x16_bf16(af0, v00, acc00, 0, 0, 0);
            acc01 = __builtin_amdgcn_mfma_f32_32x32x16_bf16(af0, v01, acc01, 0, 0, 0);
            acc00 = __builtin_amdgcn_mfma_f32_32x32x16_bf16(af1, v10, acc00, 0, 0, 0);
            acc01 = __builtin_amdgcn_mfma_f32_32x32x16_bf16(af1, v11, acc01, 0, 0, 0);
        }
        // ---- q-group 1 ----
        {
            float e[16];
#pragma unroll
            for (int r = 0; r < 16; ++r) e[r] = fast_exp2(st1[r]);
            ls1 += ((e[0] + e[1]) + (e[2] + e[3])) + ((e[4] + e[5]) + (e[6] + e[7]))
                 + ((e[8] + e[9]) + (e[10] + e[11])) + ((e[12] + e[13]) + (e[14] + e[15]));
            uint4v u0, u1;
#pragma unroll
            for (int p = 0; p < 4; ++p) u0[p] = pk2(e[2 * p], e[2 * p + 1]);
#pragma unroll
            for (int p = 0; p < 4; ++p) u1[p] = pk2(e[8 + 2 * p], e[9 + 2 * p]);
            const short8 af0 = __builtin_bit_cast(short8, u0);
            const short8 af1 = __builtin_bit_cast(short8, u1);
            acc10 = __builtin_amdgcn_mfma_f32_32x32x16_bf16(af0, v00, acc10, 0, 0, 0);
            acc11 = __builtin_amdgcn_mfma_f32_32x32x16_bf16(af0, v01, acc11, 0, 0, 0);
            acc10 = __builtin_amdgcn_mfma_f32_32x32x16_bf16(af1, v10, acc10, 0, 0, 0);
            acc11 = __builtin_amdgcn_mfma_f32_32x32x16_bf16(af1, v11, acc11, 0, 0, 0);
        }

        kf = kfn; v00 = n00; v01 = n01; v10 = n10; v11 = n11;
    }

    // per-wave partial write (bf16-packed numerators, f32 lsums)
    // pls[qt][kp][qgrp][g][l31]  (stride 128 f32 per (qt,kp) -- matches merge)
    const unsigned lsbase = ((unsigned)qt * 16u + kp) * 128u;
    wsf[PLS_F + lsbase +       g * 32u + l31] = ls0;   // qgrp 0
    wsf[PLS_F + lsbase + 64u + g * 32u + l31] = ls1;   // qgrp 1

    const unsigned pbase = ((unsigned)qt * 16u + kp) * 64u;
#pragma unroll
    for (int r = 0; r < 16; ++r) {
        const int q0 = (r & 3) + 8 * (r >> 2) + 4 * g;
        wsu[PACC_U + (pbase + q0) * 32u + l31]        = pk2(acc00[r], acc01[r]);
        wsu[PACC_U + (pbase + 32 + q0) * 32u + l31]   = pk2(acc10[r], acc11[r]);
    }
}

// ---------------- Phase C: merge 16 partials + epilogue ----------------
// 125 blocks x 256 thr; thread = (q = tid>>2, i0 = (tid&3)*8) covers
// columns i0..i0+7 and 32+i0..32+i0+7 via packed words.
__global__ __launch_bounds__(256) void pam_merge(
    const float* __restrict__ x,
    const float* __restrict__ gamma_p,
    const float* __restrict__ wsf,
    const unsigned* __restrict__ wsu,
    float* __restrict__ out)
{
    const int tid = threadIdx.x;
    const int qt  = blockIdx.x;
    const int q   = tid >> 2;
    const int i0  = (tid & 3) * 8;
    const int qgrp = q >> 5, qi = q & 31;

    float lq = 0.f;
#pragma unroll
    for (int kp = 0; kp < 16; ++kp) {
        const unsigned lb = PLS_F + ((unsigned)(qt * 16 + kp)) * 128u + qgrp * 64u + qi;
        lq += wsf[lb] + wsf[lb + 32];
    }

    float alo[8] = {}, ahi[8] = {};
#pragma unroll
    for (int kp = 0; kp < 16; ++kp) {
        const unsigned* pb = wsu + PACC_U + (((unsigned)(qt * 16 + kp)) * 64u + q) * 32u + i0;
        const uint4v w0 = *reinterpret_cast<const uint4v*>(pb);
        const uint4v w1 = *reinterpret_cast<const uint4v*>(pb + 4);
#pragma unroll
        for (int t = 0; t < 4; ++t) {
            alo[t]     += __builtin_bit_cast(float, w0[t] << 16);
            ahi[t]     += __builtin_bit_cast(float, w0[t] & 0xffff0000u);
            alo[4 + t] += __builtin_bit_cast(float, w1[t] << 16);
            ahi[4 + t] += __builtin_bit_cast(float, w1[t] & 0xffff0000u);
        }
    }

    const float sc = gamma_p[0] / lq;
    const int base = (qt * 64 + q) * 64;

    fx4 o;
#pragma unroll
    for (int h = 0; h < 2; ++h) {
        const int off = base + i0 + 4 * h;
        const fx4 xr = *reinterpret_cast<const fx4*>(x + off);
#pragma unroll
        for (int t = 0; t < 4; ++t) o[t] = alo[4 * h + t] * sc + xr[t];
        *reinterpret_cast<fx4*>(out + off) = o;
    }
#pragma unroll
    for (int h = 0; h < 2; ++h) {
        const int off = base + 32 + i0 + 4 * h;
        const fx4 xr = *reinterpret_cast<const fx4*>(x + off);
#pragma unroll
        for (int t = 0; t < 4; ++t) o[t] = ahi[4 * h + t] * sc + xr[t];
        *reinterpret_cast<fx4*>(out + off) = o;
    }
}

extern "C" void kernel_launch(void* const* d_in, const int* in_sizes, int n_in,
                              void* d_out, int out_size, void* d_ws, size_t ws_size,
                              hipStream_t stream)
{
    const float* x     = (const float*)d_in[0];
    const float* Wb    = (const float*)d_in[1];
    const float* Wc    = (const float*)d_in[2];
    const float* Wd    = (const float*)d_in[3];
    const float* gamma = (const float*)d_in[4];
    float* outp = (float*)d_out;
    unsigned short* ws = (unsigned short*)d_ws;
    float* wsf = (float*)d_ws;
    unsigned* wsu = (unsigned*)d_ws;

    hipLaunchKernelGGL(pam_proj, dim3(125), dim3(128), 0, stream, x, Wb, Wc, Wd, ws);
    hipLaunchKernelGGL(pam_attn, dim3(512), dim3(256), 0, stream,
                       (const unsigned short*)ws, wsf, wsu);
    hipLaunchKernelGGL(pam_merge, dim3(125), dim3(256), 0, stream,
                       x, gamma, (const float*)wsf, (const unsigned*)wsu, outp);
}